// Round 4
// baseline (695.398 us; speedup 1.0000x reference)
//
#include <hip/hip_runtime.h>
#include <hip/hip_bf16.h>
#include <stdint.h>

#define B_   64
#define T_   2048
#define ENC_ 1024
#define DEC_ 1024
#define A_   512
#define M_   (B_ * T_)   // 131072

#define BM 128
#define BN 256

typedef __bf16 bf16x8 __attribute__((ext_vector_type(8)));
typedef float  f32x4  __attribute__((ext_vector_type(4)));
typedef unsigned short u16;

__device__ __forceinline__ u16 f2bf(float x) {
    uint32_t u = __float_as_uint(x);
    u += 0x7FFFu + ((u >> 16) & 1u);   // round-to-nearest-even
    return (u16)(u >> 16);
}

__device__ __forceinline__ float fast_tanh(float x) {
    float ax = fabsf(x);
    float e  = __expf(-2.0f * ax);     // in (0,1]
    float t  = (1.0f - e) / (1.0f + e);
    return copysignf(t, x);
}

// ---- B pack: Bp[((ks*4+g)*512 + n)*8 + j] = bf16(U[(ks*32+g*8+j)][n]) ----
// One thread per 16B output chunk (8 bf16). 512*1024/8 = 65536 chunks.
__global__ __launch_bounds__(256) void k_pack_B(
        const float* __restrict__ U, u16* __restrict__ Bp) {
    int c = blockIdx.x * 256 + threadIdx.x;       // chunk index
    int n  = c & 511;
    int gg = (c >> 9) & 3;
    int ks = c >> 11;
    int kbase = ks * 32 + gg * 8;
    u16 w[8];
#pragma unroll
    for (int j = 0; j < 8; ++j)
        w[j] = f2bf(U[(size_t)(kbase + j) * A_ + n]);
    *(ushort4*)(Bp + (size_t)c * 8)     = *(ushort4*)&w[0];
    *(ushort4*)(Bp + (size_t)c * 8 + 4) = *(ushort4*)&w[4];
}

// ---------------- f2[b][a] = sum_e s[b][e] * W[e][a]  (fp32) ---------------
__global__ __launch_bounds__(256) void k_f2(
        const float* __restrict__ s, const float* __restrict__ W,
        float* __restrict__ f2) {
    int b = blockIdx.x;
    int a0 = threadIdx.x;
    const float* srow = s + (size_t)b * DEC_;
    float acc0 = 0.f, acc1 = 0.f;
    for (int e = 0; e < DEC_; ++e) {
        float sv = srow[e];
        acc0 = fmaf(sv, W[(size_t)e * A_ + a0],       acc0);
        acc1 = fmaf(sv, W[(size_t)e * A_ + a0 + 256], acc1);
    }
    f2[(size_t)b * A_ + a0]       = acc0;
    f2[(size_t)b * A_ + a0 + 256] = acc1;
}

// ---------------- fused GEMM + tanh + dot(V): partial e --------------------
// LDS-free, barrier-free. 2048 blocks x 512 threads (8 waves, 2x4 wave grid),
// wave tile 64x64. A fragments straight from h (fp32->bf16 in regs, L1 serves
// the 4-way intra-block row reuse); B from packed Bp (coalesced, L2-resident).
// Register software pipeline, 1 k-step ahead, statically indexed buffers.
__global__ __launch_bounds__(512) void k_gemm_e(
        const float* __restrict__ h, const u16* __restrict__ Bp,
        const float* __restrict__ f2, const float* __restrict__ V,
        float* __restrict__ e_part) {
    const int tid  = threadIdx.x;
    const int lane = tid & 63;
    const int wid  = tid >> 6;         // 0..7
    const int wr   = wid >> 2;         // 0..1
    const int wc   = wid & 3;          // 0..3
    const int lr   = lane & 15;
    const int g    = lane >> 4;

    const int idx  = blockIdx.x;       // y-pair adjacent for L3 reuse of h
    const int bx   = idx >> 1;
    const int by   = idx & 1;
    const int brow = bx * BM;
    const int bcol = by * BN;
    const int b    = brow / T_;        // uniform per block (T_ % BM == 0)

    // per-lane base pointers
    const float* arow[4];
#pragma unroll
    for (int mf = 0; mf < 4; ++mf)
        arow[mf] = h + (size_t)(brow + wr * 64 + mf * 16 + lr) * ENC_ + g * 8;
    const u16* bbase = Bp + ((size_t)g * 512 + bcol + wc * 64 + lr) * 8;

    f32x4 acc[4][4] = {};

    auto loadA = [&](int ks, f32x4 (&a)[4][2]) {
#pragma unroll
        for (int mf = 0; mf < 4; ++mf) {
            const float* src = arow[mf] + ks * 32;
            a[mf][0] = *(const f32x4*)src;
            a[mf][1] = *(const f32x4*)(src + 4);
        }
    };
    auto loadB = [&](int ks, bf16x8 (&bb)[4]) {
#pragma unroll
        for (int nf = 0; nf < 4; ++nf)
            bb[nf] = *(const bf16x8*)(bbase + (size_t)ks * 16384 + nf * 128);
    };
    auto step = [&](f32x4 (&a)[4][2], bf16x8 (&bb)[4]) {
        bf16x8 af[4];
#pragma unroll
        for (int mf = 0; mf < 4; ++mf)
#pragma unroll
            for (int j = 0; j < 4; ++j) {
                af[mf][j]     = (__bf16)a[mf][0][j];
                af[mf][j + 4] = (__bf16)a[mf][1][j];
            }
        __builtin_amdgcn_s_setprio(1);
#pragma unroll
        for (int mf = 0; mf < 4; ++mf)
#pragma unroll
            for (int nf = 0; nf < 4; ++nf)
                acc[mf][nf] = __builtin_amdgcn_mfma_f32_16x16x32_bf16(
                    af[mf], bb[nf], acc[mf][nf], 0, 0, 0);
        __builtin_amdgcn_s_setprio(0);
    };

    f32x4 a0[4][2], a1[4][2];
    bf16x8 b0[4], b1[4];
    loadA(0, a0); loadB(0, b0);
    for (int ks = 0; ks < 32; ks += 2) {
        loadA(ks + 1, a1); loadB(ks + 1, b1);   // prefetch next
        step(a0, b0);
        if (ks + 2 < 32) { loadA(ks + 2, a0); loadB(ks + 2, b0); }
        step(a1, b1);
    }

    // ---- epilogue: e_partial[m] = sum_n tanh(acc + f2) * V ----
    float vv[4], ff[4];
#pragma unroll
    for (int nf = 0; nf < 4; ++nf) {
        int n = bcol + wc * 64 + nf * 16 + lr;
        vv[nf] = V[n];
        ff[nf] = f2[(size_t)b * A_ + n];
    }
    const int p = by * 4 + wc;                    // 8 partial slices
    float* ep = e_part + (size_t)p * M_ + brow + wr * 64;
#pragma unroll
    for (int mf = 0; mf < 4; ++mf) {
        float sums[4];
#pragma unroll
        for (int i = 0; i < 4; ++i) {
            float sv = 0.f;
#pragma unroll
            for (int nf = 0; nf < 4; ++nf) {
                float x = acc[mf][nf][i] + ff[nf];
                sv = fmaf(fast_tanh(x), vv[nf], sv);
            }
#pragma unroll
            for (int m = 1; m < 16; m <<= 1)
                sv += __shfl_xor(sv, m, 64);      // reduce 16 cols
            sums[i] = sv;
        }
        if (lr == 0) {
#pragma unroll
            for (int i = 0; i < 4; ++i)
                ep[mf * 16 + g * 4 + i] = sums[i];
        }
    }
}

// ---------------- softmax over T per batch --------------------------------
__global__ __launch_bounds__(256) void k_softmax(
        const float* __restrict__ e_part, float* __restrict__ a_out) {
    const int b = blockIdx.x, tid = threadIdx.x;
    const int lane = tid & 63, w = tid >> 6;
    __shared__ float red[4], red2[4];

    float ls[8];
    float lmax = -1e30f;
#pragma unroll
    for (int i = 0; i < 8; ++i) {
        size_t m = (size_t)b * T_ + i * 256 + tid;
        float sv = 0.f;
#pragma unroll
        for (int p = 0; p < 8; ++p) sv += e_part[(size_t)p * M_ + m];
        ls[i] = sv;
        lmax = fmaxf(lmax, sv);
    }
#pragma unroll
    for (int m = 1; m < 64; m <<= 1) lmax = fmaxf(lmax, __shfl_xor(lmax, m, 64));
    if (lane == 0) red[w] = lmax;
    __syncthreads();
    float bmax = fmaxf(fmaxf(red[0], red[1]), fmaxf(red[2], red[3]));

    float lsum = 0.f;
#pragma unroll
    for (int i = 0; i < 8; ++i) { ls[i] = __expf(ls[i] - bmax); lsum += ls[i]; }
#pragma unroll
    for (int m = 1; m < 64; m <<= 1) lsum += __shfl_xor(lsum, m, 64);
    if (lane == 0) red2[w] = lsum;
    __syncthreads();
    float inv = 1.0f / (red2[0] + red2[1] + red2[2] + red2[3]);

#pragma unroll
    for (int i = 0; i < 8; ++i)
        a_out[(size_t)b * T_ + i * 256 + tid] = ls[i] * inv;
}

// ---------------- context partials: c_part[tc][b][e], tc-chunk = 128 ------
__global__ __launch_bounds__(256) void k_ctx_part(
        const float* __restrict__ h, const float* __restrict__ a,
        float* __restrict__ c_part) {
    const int b = blockIdx.x, tc = blockIdx.y, tid = threadIdx.x;
    __shared__ float alds[128];
    if (tid < 128)
        alds[tid] = a[(size_t)b * T_ + tc * 128 + tid];
    __syncthreads();

    float4 acc = {0.f, 0.f, 0.f, 0.f};
    const float* hb = h + ((size_t)b * T_ + (size_t)tc * 128) * ENC_ + tid * 4;
    for (int t = 0; t < 128; ++t) {
        float av = alds[t];
        float4 hv = *(const float4*)(hb + (size_t)t * ENC_);
        acc.x = fmaf(av, hv.x, acc.x);
        acc.y = fmaf(av, hv.y, acc.y);
        acc.z = fmaf(av, hv.z, acc.z);
        acc.w = fmaf(av, hv.w, acc.w);
    }
    *(float4*)&c_part[((size_t)(tc * 64 + b)) * ENC_ + tid * 4] = acc;
}

// ---------------- final context reduce ------------------------------------
__global__ __launch_bounds__(256) void k_ctx_final(
        const float* __restrict__ c_part, float* __restrict__ c_out) {
    int idx = blockIdx.x * 256 + threadIdx.x;   // 16384 threads
    int off = idx * 4;
    float4 sv = {0.f, 0.f, 0.f, 0.f};
#pragma unroll
    for (int tc = 0; tc < 16; ++tc) {
        float4 v = *(const float4*)&c_part[(size_t)tc * 64 * 1024 + off];
        sv.x += v.x; sv.y += v.y; sv.z += v.z; sv.w += v.w;
    }
    *(float4*)&c_out[off] = sv;
}

extern "C" void kernel_launch(void* const* d_in, const int* in_sizes, int n_in,
                              void* d_out, int out_size, void* d_ws, size_t ws_size,
                              hipStream_t stream) {
    const float* h = (const float*)d_in[0];
    const float* s = (const float*)d_in[1];
    const float* U = (const float*)d_in[2];
    const float* W = (const float*)d_in[3];
    const float* V = (const float*)d_in[4];

    float* out   = (float*)d_out;
    float* c_out = out;                         // [64][1][1024] -> 65536 floats
    float* a_out = out + 64 * 1024;             // [64][2048][1] -> 131072 floats

    char* ws = (char*)d_ws;
    u16*   Bp     = (u16*)ws;                                       // 1 MB
    float* f2     = (float*)(ws + (1 << 20));                       // 128 KB
    float* e_part = (float*)(ws + (1 << 20) + (128 << 10));         // 4 MB
    float* c_part = e_part;   // overlay: e_part dead after k_softmax

    k_pack_B<<<256, 256, 0, stream>>>(U, Bp);
    k_f2<<<64, 256, 0, stream>>>(s, W, f2);

    k_gemm_e<<<2048, 512, 0, stream>>>(h, Bp, f2, V, e_part);

    k_softmax<<<64, 256, 0, stream>>>(e_part, a_out);

    dim3 gc(64, 16);
    k_ctx_part<<<gc, 256, 0, stream>>>(h, a_out, c_part);
    k_ctx_final<<<64, 256, 0, stream>>>(c_part, c_out);
}

// Round 5
// 457.031 us; speedup vs baseline: 1.5216x; 1.5216x over previous
//
#include <hip/hip_runtime.h>
#include <hip/hip_bf16.h>
#include <stdint.h>

#define B_   64
#define T_   2048
#define ENC_ 1024
#define DEC_ 1024
#define A_   512
#define M_   (B_ * T_)   // 131072

#define BM 256
#define BN 256
#define BK 64

typedef __bf16 bf16x8 __attribute__((ext_vector_type(8)));
typedef float  f32x4  __attribute__((ext_vector_type(4)));
typedef unsigned short u16;

__device__ __forceinline__ float fast_tanh(float x) {
    float ax = fabsf(x);
    float e  = __expf(-2.0f * ax);     // in (0,1]
    float t  = (1.0f - e) / (1.0f + e);
    return copysignf(t, x);
}

// ---------------- U transpose + convert: Ut[n][k] = bf16(U[k][n]) ----------
__global__ __launch_bounds__(256) void k_transpose_U(
        const float* __restrict__ U, u16* __restrict__ Ut) {
    int idx = blockIdx.x * 256 + threadIdx.x;     // over 1024*512
    if (idx >= ENC_ * A_) return;
    int k = idx / A_, n = idx % A_;
    __bf16 v = (__bf16)U[idx];
    Ut[n * ENC_ + k] = *(u16*)&v;
}

// ---------------- f2[b][a] = sum_e s[b][e] * W[e][a]  (fp32) ---------------
__global__ __launch_bounds__(256) void k_f2(
        const float* __restrict__ s, const float* __restrict__ W,
        float* __restrict__ f2) {
    int b = blockIdx.x;
    int a0 = threadIdx.x;
    const float* srow = s + (size_t)b * DEC_;
    float acc0 = 0.f, acc1 = 0.f;
    for (int e = 0; e < DEC_; ++e) {
        float sv = srow[e];
        acc0 = fmaf(sv, W[(size_t)e * A_ + a0],       acc0);
        acc1 = fmaf(sv, W[(size_t)e * A_ + a0 + 256], acc1);
    }
    f2[(size_t)b * A_ + a0]       = acc0;
    f2[(size_t)b * A_ + a0 + 256] = acc1;
}

// ---------------- fused GEMM + tanh + dot(V): partial e --------------------
// 8-phase counted-vmcnt schedule (m201 template adapted to fp32 A).
// grid 1024 (=512 row-blocks x 2 col-blocks, pair-adjacent), 512 threads,
// 8 waves (2M x 4N), wave tile 128x64. LDS 128KB: dbuf x (A 32KB + B 32KB).
// XOR-swizzle (T2): phys_u16 = logical ^ ((row&7)<<3); B staged via
// global_load_lds with pre-swizzled global source; A reg-staged (T14 split:
// loads in ph0/1, cvt+ds_write in ph2/3). vmcnt(0) only at phase 3/7 end.
__global__ __launch_bounds__(512) void k_gemm_e(
        const float* __restrict__ h, const u16* __restrict__ Ut,
        const float* __restrict__ f2, const float* __restrict__ V,
        float* __restrict__ e_part) {
    __shared__ u16 Ab[2][BM * BK];     // 2 x 32 KB
    __shared__ u16 Bb[2][BN * BK];     // 2 x 32 KB

    const int tid  = threadIdx.x;
    const int lane = tid & 63;
    const int wid  = tid >> 6;         // 0..7
    const int wr   = wid >> 2;         // 0..1
    const int wc   = wid & 3;          // 0..3
    const int lr   = lane & 15;
    const int g    = lane >> 4;
    const int swl  = (lr & 7) << 3;    // read-side XOR (u16 units)

    const int idx  = blockIdx.x;
    const int bx   = idx >> 1;
    const int by   = idx & 1;
    const int brow = bx * BM;
    const int bcol = by * BN;
    const int b    = brow / T_;        // uniform per block (T_ % BM == 0)

    f32x4 acc[8][4] = {};
    bf16x8 bfr[4][2];                  // B frags, live across 4 phases
    f32x4 ar0[4], ar1[4];              // in-flight A halves (fp32)

    auto loadAhalf = [&](int kb, int hf, f32x4 (&r)[4]) {
        int row = hf * 128 + (tid >> 2);
        int col = (tid & 3) * 16;
        const float* src = h + (size_t)(brow + row) * ENC_ + kb + col;
        r[0] = *(const f32x4*)src;       r[1] = *(const f32x4*)(src + 4);
        r[2] = *(const f32x4*)(src + 8); r[3] = *(const f32x4*)(src + 12);
    };
    auto writeAhalf = [&](u16* A, int hf, const f32x4 (&r)[4]) {
        int row = hf * 128 + (tid >> 2);
        int col = (tid & 3) * 16;
        int swr = (row & 7) << 3;
        bf16x8 lo, hi;
#pragma unroll
        for (int j = 0; j < 4; ++j) {
            lo[j] = (__bf16)r[0][j]; lo[j + 4] = (__bf16)r[1][j];
            hi[j] = (__bf16)r[2][j]; hi[j + 4] = (__bf16)r[3][j];
        }
        *(bf16x8*)&A[(row * 64 + col)     ^ swr] = lo;
        *(bf16x8*)&A[(row * 64 + col + 8) ^ swr] = hi;
    };
    auto stageBhalf = [&](u16* Bd, int kb, int hf) {
#pragma unroll
        for (int it = 0; it < 2; ++it) {
            int G  = hf * 1024 + it * 512 + tid;      // 16B granule
            int n  = G >> 3;
            int kc = ((G & 7) ^ (n & 7)) << 3;        // pre-swizzled source
            const u16* src = Ut + (size_t)(bcol + n) * ENC_ + kb + kc;
            u16* dst = Bd + (size_t)(hf * 1024 + it * 512 + wid * 64) * 8;
            __builtin_amdgcn_global_load_lds(
                (const __attribute__((address_space(1))) void*)src,
                (__attribute__((address_space(3))) void*)dst, 16, 0, 0);
        }
    };
    auto readA2 = [&](const u16* A, int mf, bf16x8 &f0, bf16x8 &f1) {
        int base = (wr * 128 + mf * 16 + lr) * 64;    // row&7 == lr&7
        f0 = *(const bf16x8*)&A[(base + g * 8)      ^ swl];
        f1 = *(const bf16x8*)&A[(base + 32 + g * 8) ^ swl];
    };
    auto readB = [&](const u16* Bc) {
#pragma unroll
        for (int nf = 0; nf < 4; ++nf) {
            int base = (wc * 64 + nf * 16 + lr) * 64; // n&7 == lr&7
            bfr[nf][0] = *(const bf16x8*)&Bc[(base + g * 8)      ^ swl];
            bfr[nf][1] = *(const bf16x8*)&Bc[(base + 32 + g * 8) ^ swl];
        }
    };
    auto mfma_pair = [&](f32x4 (&c0)[4], f32x4 (&c1)[4],
                         bf16x8 x0, bf16x8 x1, bf16x8 y0, bf16x8 y1) {
        __builtin_amdgcn_s_setprio(1);
#pragma unroll
        for (int nf = 0; nf < 4; ++nf) {
            c0[nf] = __builtin_amdgcn_mfma_f32_16x16x32_bf16(x0, bfr[nf][0], c0[nf], 0, 0, 0);
            c0[nf] = __builtin_amdgcn_mfma_f32_16x16x32_bf16(x1, bfr[nf][1], c0[nf], 0, 0, 0);
            c1[nf] = __builtin_amdgcn_mfma_f32_16x16x32_bf16(y0, bfr[nf][0], c1[nf], 0, 0, 0);
            c1[nf] = __builtin_amdgcn_mfma_f32_16x16x32_bf16(y1, bfr[nf][1], c1[nf], 0, 0, 0);
        }
        __builtin_amdgcn_s_setprio(0);
    };

#define BAR()   __builtin_amdgcn_s_barrier()
#define LGKM0() asm volatile("s_waitcnt lgkmcnt(0)" ::: "memory")
#define VM0()   asm volatile("s_waitcnt vmcnt(0)" ::: "memory")

    // group: compute K-tile from (Ac,Bc); stage K-tile at k=ks into (As,Bs).
    auto group = [&](const u16* Ac, const u16* Bc, u16* As, u16* Bs,
                     int ks, bool stg) {
        bf16x8 p0, p1, q0, q1;
        // ---- phase 0 ----
        readB(Bc);
        readA2(Ac, 0, p0, p1); readA2(Ac, 1, q0, q1);
        if (stg) { loadAhalf(ks, 0, ar0); stageBhalf(Bs, ks, 0); }
        BAR(); LGKM0();
        mfma_pair(acc[0], acc[1], p0, p1, q0, q1);
        BAR();
        // ---- phase 1 ----
        readA2(Ac, 2, p0, p1); readA2(Ac, 3, q0, q1);
        if (stg) { loadAhalf(ks, 1, ar1); stageBhalf(Bs, ks, 1); }
        BAR(); LGKM0();
        mfma_pair(acc[2], acc[3], p0, p1, q0, q1);
        BAR();
        // ---- phase 2 ----  (compiler inserts counted vmcnt for ar0 use)
        if (stg) writeAhalf(As, 0, ar0);
        readA2(Ac, 4, p0, p1); readA2(Ac, 5, q0, q1);
        BAR(); LGKM0();
        mfma_pair(acc[4], acc[5], p0, p1, q0, q1);
        BAR();
        // ---- phase 3 ----
        if (stg) writeAhalf(As, 1, ar1);
        readA2(Ac, 6, p0, p1); readA2(Ac, 7, q0, q1);
        BAR(); LGKM0();
        mfma_pair(acc[6], acc[7], p0, p1, q0, q1);
        VM0();                 // gate: staged B gload_lds retired before
        BAR();                 // anyone crosses into the consuming group
    };

    // ---- prologue: stage tile 0 into buffer 0, full drain ----
    loadAhalf(0, 0, ar0); loadAhalf(0, 1, ar1);
    stageBhalf(Bb[0], 0, 0); stageBhalf(Bb[0], 0, 1);
    writeAhalf(Ab[0], 0, ar0);
    writeAhalf(Ab[0], 1, ar1);
    VM0(); LGKM0(); BAR();

    for (int i = 0; i < 8; ++i) {
        group(Ab[0], Bb[0], Ab[1], Bb[1], (2 * i + 1) * BK, true);
        group(Ab[1], Bb[1], Ab[0], Bb[0], (2 * i + 2) * BK, i < 7);
    }

    // ---- epilogue: e_partial[m] = sum_n tanh(acc + f2) * V ----
    float vv[4], ff[4];
#pragma unroll
    for (int nf = 0; nf < 4; ++nf) {
        int n = bcol + wc * 64 + nf * 16 + lr;
        vv[nf] = V[n];
        ff[nf] = f2[(size_t)b * A_ + n];
    }
    const int p = by * 4 + wc;                    // 8 partial slices
    float* ep = e_part + (size_t)p * M_ + brow + wr * 128;
#pragma unroll
    for (int mf = 0; mf < 8; ++mf) {
        float sums[4];
#pragma unroll
        for (int i = 0; i < 4; ++i) {
            float sv = 0.f;
#pragma unroll
            for (int nf = 0; nf < 4; ++nf) {
                float x = acc[mf][nf][i] + ff[nf];
                sv = fmaf(fast_tanh(x), vv[nf], sv);
            }
#pragma unroll
            for (int m = 1; m < 16; m <<= 1)
                sv += __shfl_xor(sv, m, 64);      // reduce 16 cols
            sums[i] = sv;
        }
        if (lr == 0) {
#pragma unroll
            for (int i = 0; i < 4; ++i)
                ep[mf * 16 + g * 4 + i] = sums[i];
        }
    }
#undef BAR
#undef LGKM0
#undef VM0
}

// ---------------- softmax over T per batch --------------------------------
__global__ __launch_bounds__(256) void k_softmax(
        const float* __restrict__ e_part, float* __restrict__ a_out) {
    const int b = blockIdx.x, tid = threadIdx.x;
    const int lane = tid & 63, w = tid >> 6;
    __shared__ float red[4], red2[4];

    float ls[8];
    float lmax = -1e30f;
#pragma unroll
    for (int i = 0; i < 8; ++i) {
        size_t m = (size_t)b * T_ + i * 256 + tid;
        float sv = 0.f;
#pragma unroll
        for (int p = 0; p < 8; ++p) sv += e_part[(size_t)p * M_ + m];
        ls[i] = sv;
        lmax = fmaxf(lmax, sv);
    }
#pragma unroll
    for (int m = 1; m < 64; m <<= 1) lmax = fmaxf(lmax, __shfl_xor(lmax, m, 64));
    if (lane == 0) red[w] = lmax;
    __syncthreads();
    float bmax = fmaxf(fmaxf(red[0], red[1]), fmaxf(red[2], red[3]));

    float lsum = 0.f;
#pragma unroll
    for (int i = 0; i < 8; ++i) { ls[i] = __expf(ls[i] - bmax); lsum += ls[i]; }
#pragma unroll
    for (int m = 1; m < 64; m <<= 1) lsum += __shfl_xor(lsum, m, 64);
    if (lane == 0) red2[w] = lsum;
    __syncthreads();
    float inv = 1.0f / (red2[0] + red2[1] + red2[2] + red2[3]);

#pragma unroll
    for (int i = 0; i < 8; ++i)
        a_out[(size_t)b * T_ + i * 256 + tid] = ls[i] * inv;
}

// ---------------- context partials: c_part[tc][b][e], tc-chunk = 128 ------
__global__ __launch_bounds__(256) void k_ctx_part(
        const float* __restrict__ h, const float* __restrict__ a,
        float* __restrict__ c_part) {
    const int b = blockIdx.x, tc = blockIdx.y, tid = threadIdx.x;
    __shared__ float alds[128];
    if (tid < 128)
        alds[tid] = a[(size_t)b * T_ + tc * 128 + tid];
    __syncthreads();

    float4 acc = {0.f, 0.f, 0.f, 0.f};
    const float* hb = h + ((size_t)b * T_ + (size_t)tc * 128) * ENC_ + tid * 4;
    for (int t = 0; t < 128; ++t) {
        float av = alds[t];
        float4 hv = *(const float4*)(hb + (size_t)t * ENC_);
        acc.x = fmaf(av, hv.x, acc.x);
        acc.y = fmaf(av, hv.y, acc.y);
        acc.z = fmaf(av, hv.z, acc.z);
        acc.w = fmaf(av, hv.w, acc.w);
    }
    *(float4*)&c_part[((size_t)(tc * 64 + b)) * ENC_ + tid * 4] = acc;
}

// ---------------- final context reduce ------------------------------------
__global__ __launch_bounds__(256) void k_ctx_final(
        const float* __restrict__ c_part, float* __restrict__ c_out) {
    int idx = blockIdx.x * 256 + threadIdx.x;   // 16384 threads
    int off = idx * 4;
    float4 sv = {0.f, 0.f, 0.f, 0.f};
#pragma unroll
    for (int tc = 0; tc < 16; ++tc) {
        float4 v = *(const float4*)&c_part[(size_t)tc * 64 * 1024 + off];
        sv.x += v.x; sv.y += v.y; sv.z += v.z; sv.w += v.w;
    }
    *(float4*)&c_out[off] = sv;
}

extern "C" void kernel_launch(void* const* d_in, const int* in_sizes, int n_in,
                              void* d_out, int out_size, void* d_ws, size_t ws_size,
                              hipStream_t stream) {
    const float* h = (const float*)d_in[0];
    const float* s = (const float*)d_in[1];
    const float* U = (const float*)d_in[2];
    const float* W = (const float*)d_in[3];
    const float* V = (const float*)d_in[4];

    float* out   = (float*)d_out;
    float* c_out = out;                         // [64][1][1024] -> 65536 floats
    float* a_out = out + 64 * 1024;             // [64][2048][1] -> 131072 floats

    char* ws = (char*)d_ws;
    u16*   Ut     = (u16*)ws;                                       // 1 MB
    float* f2     = (float*)(ws + (1 << 20));                       // 128 KB
    float* e_part = (float*)(ws + (1 << 20) + (128 << 10));         // 4 MB
    float* c_part = e_part;   // overlay: e_part dead after k_softmax

    k_transpose_U<<<2048, 256, 0, stream>>>(U, Ut);
    k_f2<<<64, 256, 0, stream>>>(s, W, f2);

    k_gemm_e<<<1024, 512, 0, stream>>>(h, Ut, f2, V, e_part);

    k_softmax<<<64, 256, 0, stream>>>(e_part, a_out);

    dim3 gc(64, 16);
    k_ctx_part<<<gc, 256, 0, stream>>>(h, a_out, c_part);
    k_ctx_final<<<64, 256, 0, stream>>>(c_part, c_out);
}

// Round 6
// 417.755 us; speedup vs baseline: 1.6646x; 1.0940x over previous
//
#include <hip/hip_runtime.h>
#include <hip/hip_bf16.h>
#include <stdint.h>

#define B_   64
#define T_   2048
#define ENC_ 1024
#define DEC_ 1024
#define A_   512
#define M_   (B_ * T_)   // 131072

#define BM 256
#define BN 256
#define BK 64

typedef __bf16 bf16x8 __attribute__((ext_vector_type(8)));
typedef float  f32x4  __attribute__((ext_vector_type(4)));
typedef unsigned short u16;

__device__ __forceinline__ float fast_tanh(float x) {
    float ax = fabsf(x);
    float e  = __expf(-2.0f * ax);     // in (0,1]
    float t  = (1.0f - e) / (1.0f + e);
    return copysignf(t, x);
}

// ---------------- U transpose + convert: Ut[n][k] = bf16(U[k][n]) ----------
__global__ __launch_bounds__(256) void k_transpose_U(
        const float* __restrict__ U, u16* __restrict__ Ut) {
    int idx = blockIdx.x * 256 + threadIdx.x;     // over 1024*512
    if (idx >= ENC_ * A_) return;
    int k = idx / A_, n = idx % A_;
    __bf16 v = (__bf16)U[idx];
    Ut[n * ENC_ + k] = *(u16*)&v;
}

// ---------------- f2[b][a] = sum_e s[b][e] * W[e][a]  (fp32) ---------------
__global__ __launch_bounds__(256) void k_f2(
        const float* __restrict__ s, const float* __restrict__ W,
        float* __restrict__ f2) {
    int b = blockIdx.x;
    int a0 = threadIdx.x;
    const float* srow = s + (size_t)b * DEC_;
    float acc0 = 0.f, acc1 = 0.f;
    for (int e = 0; e < DEC_; ++e) {
        float sv = srow[e];
        acc0 = fmaf(sv, W[(size_t)e * A_ + a0],       acc0);
        acc1 = fmaf(sv, W[(size_t)e * A_ + a0 + 256], acc1);
    }
    f2[(size_t)b * A_ + a0]       = acc0;
    f2[(size_t)b * A_ + a0 + 256] = acc1;
}

// ---------------- fused GEMM + tanh + dot(V): partial e --------------------
// 8-phase schedule, COUNTED vmcnt (T4): B(t+1) staged ph0/1, A(t+1) ds_write
// ph2/3 from regs, A(t+2) global loads issued ph2/3 into the other reg set.
// Group-end wait = vmcnt(8): only the 4 B gload_lds drain; the 8 A loads
// stay in flight across the barrier. vmcnt(0) never in steady state.
__global__ __launch_bounds__(512) void k_gemm_e(
        const float* __restrict__ h, const u16* __restrict__ Ut,
        const float* __restrict__ f2, const float* __restrict__ V,
        float* __restrict__ e_part) {
    __shared__ u16 Ab[2][BM * BK];     // 2 x 32 KB
    __shared__ u16 Bb[2][BN * BK];     // 2 x 32 KB

    const int tid  = threadIdx.x;
    const int lane = tid & 63;
    const int wid  = tid >> 6;         // 0..7
    const int wr   = wid >> 2;         // 0..1
    const int wc   = wid & 3;          // 0..3
    const int lr   = lane & 15;
    const int g    = lane >> 4;
    const int swl  = (lr & 7) << 3;    // read-side XOR (u16 units)

    const int idx  = blockIdx.x;
    const int bx   = idx >> 1;
    const int by   = idx & 1;
    const int brow = bx * BM;
    const int bcol = by * BN;
    const int b    = brow / T_;        // uniform per block (T_ % BM == 0)

    f32x4 acc[8][4] = {};
    bf16x8 bfr[4][2];                  // B frags, live across one group
    f32x4 arX[2][4], arY[2][4];        // two in-flight A tiles (fp32)

    auto loadAhalf = [&](int kb, int hf, f32x4 (&r)[4]) {
        int row = hf * 128 + (tid >> 2);
        int col = (tid & 3) * 16;
        const float* src = h + (size_t)(brow + row) * ENC_ + kb + col;
        r[0] = *(const f32x4*)src;       r[1] = *(const f32x4*)(src + 4);
        r[2] = *(const f32x4*)(src + 8); r[3] = *(const f32x4*)(src + 12);
    };
    auto writeAhalf = [&](u16* A, int hf, const f32x4 (&r)[4]) {
        int row = hf * 128 + (tid >> 2);
        int col = (tid & 3) * 16;
        int swr = (row & 7) << 3;
        bf16x8 lo, hi;
#pragma unroll
        for (int j = 0; j < 4; ++j) {
            lo[j] = (__bf16)r[0][j]; lo[j + 4] = (__bf16)r[1][j];
            hi[j] = (__bf16)r[2][j]; hi[j + 4] = (__bf16)r[3][j];
        }
        *(bf16x8*)&A[(row * 64 + col)     ^ swr] = lo;
        *(bf16x8*)&A[(row * 64 + col + 8) ^ swr] = hi;
    };
    auto stageBhalf = [&](u16* Bd, int kb, int hf) {
#pragma unroll
        for (int it = 0; it < 2; ++it) {
            int G  = hf * 1024 + it * 512 + tid;      // 16B granule
            int n  = G >> 3;
            int kc = ((G & 7) ^ (n & 7)) << 3;        // pre-swizzled source
            const u16* src = Ut + (size_t)(bcol + n) * ENC_ + kb + kc;
            u16* dst = Bd + (size_t)(hf * 1024 + it * 512 + wid * 64) * 8;
            __builtin_amdgcn_global_load_lds(
                (const __attribute__((address_space(1))) void*)src,
                (__attribute__((address_space(3))) void*)dst, 16, 0, 0);
        }
    };
    auto readA2 = [&](const u16* A, int mf, bf16x8 &f0, bf16x8 &f1) {
        int base = (wr * 128 + mf * 16 + lr) * 64;    // row&7 == lr&7
        f0 = *(const bf16x8*)&A[(base + g * 8)      ^ swl];
        f1 = *(const bf16x8*)&A[(base + 32 + g * 8) ^ swl];
    };
    auto readB = [&](const u16* Bc) {
#pragma unroll
        for (int nf = 0; nf < 4; ++nf) {
            int base = (wc * 64 + nf * 16 + lr) * 64; // n&7 == lr&7
            bfr[nf][0] = *(const bf16x8*)&Bc[(base + g * 8)      ^ swl];
            bfr[nf][1] = *(const bf16x8*)&Bc[(base + 32 + g * 8) ^ swl];
        }
    };
    auto mfma_pair = [&](f32x4 (&c0)[4], f32x4 (&c1)[4],
                         bf16x8 x0, bf16x8 x1, bf16x8 y0, bf16x8 y1) {
        __builtin_amdgcn_s_setprio(1);
#pragma unroll
        for (int nf = 0; nf < 4; ++nf) {
            c0[nf] = __builtin_amdgcn_mfma_f32_16x16x32_bf16(x0, bfr[nf][0], c0[nf], 0, 0, 0);
            c0[nf] = __builtin_amdgcn_mfma_f32_16x16x32_bf16(x1, bfr[nf][1], c0[nf], 0, 0, 0);
            c1[nf] = __builtin_amdgcn_mfma_f32_16x16x32_bf16(y0, bfr[nf][0], c1[nf], 0, 0, 0);
            c1[nf] = __builtin_amdgcn_mfma_f32_16x16x32_bf16(y1, bfr[nf][1], c1[nf], 0, 0, 0);
        }
        __builtin_amdgcn_s_setprio(0);
    };

#define BAR()   __builtin_amdgcn_s_barrier()
#define LGKM0() asm volatile("s_waitcnt lgkmcnt(0)" ::: "memory")
#define VMC(n)  asm volatile("s_waitcnt vmcnt(" #n ")" ::: "memory")

    // group: compute tile in (Ac,Bc); stage tile tS into (As,Bs) [B from
    // global, A from arW regs]; issue global loads of tile tL into arL.
    auto group = [&](const u16* Ac, const u16* Bc, u16* As, u16* Bs,
                     int tS, int tL, f32x4 (&arW)[2][4], f32x4 (&arL)[2][4],
                     bool last) {
        bf16x8 p0, p1, q0, q1;
        // ---- phase 0 ----
        if (tS < 16) stageBhalf(Bs, tS * BK, 0);
        readB(Bc);
        readA2(Ac, 0, p0, p1); readA2(Ac, 1, q0, q1);
        BAR(); LGKM0();
        mfma_pair(acc[0], acc[1], p0, p1, q0, q1);
        BAR();
        // ---- phase 1 ----
        if (tS < 16) stageBhalf(Bs, tS * BK, 1);
        readA2(Ac, 2, p0, p1); readA2(Ac, 3, q0, q1);
        BAR(); LGKM0();
        mfma_pair(acc[2], acc[3], p0, p1, q0, q1);
        BAR();
        // ---- phase 2 ----
        if (tS < 16) writeAhalf(As, 0, arW[0]);   // compiler waits arW regs
        if (tL < 16) loadAhalf(tL * BK, 0, arL[0]);
        readA2(Ac, 4, p0, p1); readA2(Ac, 5, q0, q1);
        BAR(); LGKM0();
        mfma_pair(acc[4], acc[5], p0, p1, q0, q1);
        BAR();
        // ---- phase 3 ----
        if (tS < 16) writeAhalf(As, 1, arW[1]);
        if (tL < 16) loadAhalf(tL * BK, 1, arL[1]);
        readA2(Ac, 6, p0, p1); readA2(Ac, 7, q0, q1);
        BAR(); LGKM0();
        mfma_pair(acc[6], acc[7], p0, p1, q0, q1);
        if (!last) {
            if (tL < 16) { VMC(8); }   // drain B(tS); A(tL) stays in flight
            else         { VMC(0); }   // no A issued this group: full drain
        }
        BAR();
    };

    // ---- prologue ----
    loadAhalf(0, 0, arX[0]); loadAhalf(0, 1, arX[1]);   // tile 0 -> regs
    stageBhalf(Bb[0], 0, 0); stageBhalf(Bb[0], 0, 1);   // B tile 0
    writeAhalf(Ab[0], 0, arX[0]);        // waits tile-0 loads (compiler)
    writeAhalf(Ab[0], 1, arX[1]);
    loadAhalf(BK, 0, arX[0]); loadAhalf(BK, 1, arX[1]); // tile 1 -> arX
    VMC(8);                              // B tile 0 done; tile-1 A in flight
    LGKM0(); BAR();

    for (int i = 0; i < 8; ++i) {
        group(Ab[0], Bb[0], Ab[1], Bb[1], 2 * i + 1, 2 * i + 2, arX, arY, false);
        group(Ab[1], Bb[1], Ab[0], Bb[0], 2 * i + 2, 2 * i + 3, arY, arX, i == 7);
    }

    // ---- epilogue: e_partial[m] = sum_n tanh(acc + f2) * V ----
    float vv[4], ff[4];
#pragma unroll
    for (int nf = 0; nf < 4; ++nf) {
        int n = bcol + wc * 64 + nf * 16 + lr;
        vv[nf] = V[n];
        ff[nf] = f2[(size_t)b * A_ + n];
    }
    const int p = by * 4 + wc;                    // 8 partial slices
    float* ep = e_part + (size_t)p * M_ + brow + wr * 128;
#pragma unroll
    for (int mf = 0; mf < 8; ++mf) {
        float sums[4];
#pragma unroll
        for (int i = 0; i < 4; ++i) {
            float sv = 0.f;
#pragma unroll
            for (int nf = 0; nf < 4; ++nf) {
                float x = acc[mf][nf][i] + ff[nf];
                sv = fmaf(fast_tanh(x), vv[nf], sv);
            }
#pragma unroll
            for (int m = 1; m < 16; m <<= 1)
                sv += __shfl_xor(sv, m, 64);      // reduce 16 cols
            sums[i] = sv;
        }
        if (lr == 0) {
#pragma unroll
            for (int i = 0; i < 4; ++i)
                ep[mf * 16 + g * 4 + i] = sums[i];
        }
    }
#undef BAR
#undef LGKM0
#undef VMC
}

// ---------------- softmax over T per batch --------------------------------
__global__ __launch_bounds__(256) void k_softmax(
        const float* __restrict__ e_part, float* __restrict__ a_out) {
    const int b = blockIdx.x, tid = threadIdx.x;
    const int lane = tid & 63, w = tid >> 6;
    __shared__ float red[4], red2[4];

    float ls[8];
    float lmax = -1e30f;
#pragma unroll
    for (int i = 0; i < 8; ++i) {
        size_t m = (size_t)b * T_ + i * 256 + tid;
        float sv = 0.f;
#pragma unroll
        for (int p = 0; p < 8; ++p) sv += e_part[(size_t)p * M_ + m];
        ls[i] = sv;
        lmax = fmaxf(lmax, sv);
    }
#pragma unroll
    for (int m = 1; m < 64; m <<= 1) lmax = fmaxf(lmax, __shfl_xor(lmax, m, 64));
    if (lane == 0) red[w] = lmax;
    __syncthreads();
    float bmax = fmaxf(fmaxf(red[0], red[1]), fmaxf(red[2], red[3]));

    float lsum = 0.f;
#pragma unroll
    for (int i = 0; i < 8; ++i) { ls[i] = __expf(ls[i] - bmax); lsum += ls[i]; }
#pragma unroll
    for (int m = 1; m < 64; m <<= 1) lsum += __shfl_xor(lsum, m, 64);
    if (lane == 0) red2[w] = lsum;
    __syncthreads();
    float inv = 1.0f / (red2[0] + red2[1] + red2[2] + red2[3]);

#pragma unroll
    for (int i = 0; i < 8; ++i)
        a_out[(size_t)b * T_ + i * 256 + tid] = ls[i] * inv;
}

// ---------------- context partials: c_part[tc][b][e], tc-chunk = 128 ------
__global__ __launch_bounds__(256) void k_ctx_part(
        const float* __restrict__ h, const float* __restrict__ a,
        float* __restrict__ c_part) {
    const int b = blockIdx.x, tc = blockIdx.y, tid = threadIdx.x;
    __shared__ float alds[128];
    if (tid < 128)
        alds[tid] = a[(size_t)b * T_ + tc * 128 + tid];
    __syncthreads();

    float4 acc = {0.f, 0.f, 0.f, 0.f};
    const float* hb = h + ((size_t)b * T_ + (size_t)tc * 128) * ENC_ + tid * 4;
    for (int t = 0; t < 128; ++t) {
        float av = alds[t];
        float4 hv = *(const float4*)(hb + (size_t)t * ENC_);
        acc.x = fmaf(av, hv.x, acc.x);
        acc.y = fmaf(av, hv.y, acc.y);
        acc.z = fmaf(av, hv.z, acc.z);
        acc.w = fmaf(av, hv.w, acc.w);
    }
    *(float4*)&c_part[((size_t)(tc * 64 + b)) * ENC_ + tid * 4] = acc;
}

// ---------------- final context reduce ------------------------------------
__global__ __launch_bounds__(256) void k_ctx_final(
        const float* __restrict__ c_part, float* __restrict__ c_out) {
    int idx = blockIdx.x * 256 + threadIdx.x;   // 16384 threads
    int off = idx * 4;
    float4 sv = {0.f, 0.f, 0.f, 0.f};
#pragma unroll
    for (int tc = 0; tc < 16; ++tc) {
        float4 v = *(const float4*)&c_part[(size_t)tc * 64 * 1024 + off];
        sv.x += v.x; sv.y += v.y; sv.z += v.z; sv.w += v.w;
    }
    *(float4*)&c_out[off] = sv;
}

extern "C" void kernel_launch(void* const* d_in, const int* in_sizes, int n_in,
                              void* d_out, int out_size, void* d_ws, size_t ws_size,
                              hipStream_t stream) {
    const float* h = (const float*)d_in[0];
    const float* s = (const float*)d_in[1];
    const float* U = (const float*)d_in[2];
    const float* W = (const float*)d_in[3];
    const float* V = (const float*)d_in[4];

    float* out   = (float*)d_out;
    float* c_out = out;                         // [64][1][1024] -> 65536 floats
    float* a_out = out + 64 * 1024;             // [64][2048][1] -> 131072 floats

    char* ws = (char*)d_ws;
    u16*   Ut     = (u16*)ws;                                       // 1 MB
    float* f2     = (float*)(ws + (1 << 20));                       // 128 KB
    float* e_part = (float*)(ws + (1 << 20) + (128 << 10));         // 4 MB
    float* c_part = e_part;   // overlay: e_part dead after k_softmax

    k_transpose_U<<<2048, 256, 0, stream>>>(U, Ut);
    k_f2<<<64, 256, 0, stream>>>(s, W, f2);

    k_gemm_e<<<1024, 512, 0, stream>>>(h, Ut, f2, V, e_part);

    k_softmax<<<64, 256, 0, stream>>>(e_part, a_out);

    dim3 gc(64, 16);
    k_ctx_part<<<gc, 256, 0, stream>>>(h, a_out, c_part);
    k_ctx_final<<<64, 256, 0, stream>>>(c_part, c_out);
}

// Round 7
// 346.057 us; speedup vs baseline: 2.0095x; 1.2072x over previous
//
#include <hip/hip_runtime.h>
#include <hip/hip_bf16.h>
#include <stdint.h>

#define B_   64
#define T_   2048
#define ENC_ 1024
#define DEC_ 1024
#define A_   512
#define M_   (B_ * T_)   // 131072

#define BM 128
#define BN 256
#define BK 64

typedef __bf16 bf16x8 __attribute__((ext_vector_type(8)));
typedef float  f32x4  __attribute__((ext_vector_type(4)));
typedef unsigned short u16;
typedef u16 u16x8 __attribute__((ext_vector_type(8)));

__device__ __forceinline__ float fast_tanh(float x) {
    float ax = fabsf(x);
    float e  = __expf(-2.0f * ax);     // in (0,1]
    float t  = (1.0f - e) / (1.0f + e);
    return copysignf(t, x);
}

// ---------------- U transpose + convert: Ut[n][k] = bf16(U[k][n]) ----------
__global__ __launch_bounds__(256) void k_transpose_U(
        const float* __restrict__ U, u16* __restrict__ Ut) {
    int idx = blockIdx.x * 256 + threadIdx.x;     // over 1024*512
    if (idx >= ENC_ * A_) return;
    int k = idx / A_, n = idx % A_;
    __bf16 v = (__bf16)U[idx];
    Ut[n * ENC_ + k] = *(u16*)&v;
}

// ---------------- f2[b][a] = sum_e s[b][e] * W[e][a]  (fp32) ---------------
__global__ __launch_bounds__(256) void k_f2(
        const float* __restrict__ s, const float* __restrict__ W,
        float* __restrict__ f2) {
    int b = blockIdx.x;
    int a0 = threadIdx.x;
    const float* srow = s + (size_t)b * DEC_;
    float acc0 = 0.f, acc1 = 0.f;
    for (int e = 0; e < DEC_; ++e) {
        float sv = srow[e];
        acc0 = fmaf(sv, W[(size_t)e * A_ + a0],       acc0);
        acc1 = fmaf(sv, W[(size_t)e * A_ + a0 + 256], acc1);
    }
    f2[(size_t)b * A_ + a0]       = acc0;
    f2[(size_t)b * A_ + a0 + 256] = acc1;
}

// ---------------- fused GEMM + tanh + dot(V): partial e --------------------
// 2048 blocks x 512 threads (8 waves, 2x4), wave tile 64x64 (acc = 64 regs).
// SINGLE-buffered 48 KB LDS, plain 2-barrier loop. The win is occupancy:
// launch_bounds(512,4) caps unified regs at 128/thread (64 acc + 64 working)
// -> 2 blocks/CU; the co-resident block's compute covers this block's
// staging burst + barrier drain (m97-style implicit overlap).
// XCD-aware remap: the two blocks sharing an A row-panel (bcol 0/256) land
// on the SAME XCD, adjacent in dispatch order -> panel L2/L3 reuse.
// T2 swizzle: phys_u16 = logical ^ ((row&7)<<3); B via global_load_lds with
// pre-swizzled SOURCE, A reg-staged with swizzled ds_write.
__global__ __launch_bounds__(512, 4) void k_gemm_e(
        const float* __restrict__ h, const u16* __restrict__ Ut,
        const float* __restrict__ f2, const float* __restrict__ V,
        float* __restrict__ e_part) {
    __shared__ u16 Alds[BM * BK];      // 16 KB, swizzled
    __shared__ u16 Blds[BN * BK];      // 32 KB, swizzled

    const int tid  = threadIdx.x;
    const int lane = tid & 63;
    const int wid  = tid >> 6;         // 0..7
    const int wr   = wid >> 2;         // 0..1
    const int wc   = wid & 3;          // 0..3
    const int lr   = lane & 15;
    const int g    = lane >> 4;
    const int sw   = (lr & 7) << 3;    // read-side XOR (u16 units)

    // XCD-aware remap: d -> (xcd = d&7, s = d>>3); pair member m = s&1.
    const int d    = blockIdx.x;
    const int xcd  = d & 7;
    const int s    = d >> 3;           // 0..255 per XCD
    const int m    = s & 1;
    const int pair = xcd * 128 + (s >> 1);   // 0..1023
    const int brow = pair * BM;
    const int bcol = m * BN;
    const int b    = brow / T_;        // uniform per block (T_ % BM == 0)

    f32x4 acc[4][4] = {};              // 64 f32 -> AGPRs

    for (int kt = 0; kt < ENC_ / BK; ++kt) {
        const int k0 = kt * BK;

        // ---- stage B: global_load_lds, LINEAR dest + pre-swizzled SOURCE --
#pragma unroll
        for (int it = 0; it < 4; ++it) {
            int G  = it * 512 + tid;                  // 16B granule index
            int n  = G >> 3;
            int kc = ((G & 7) ^ (n & 7)) << 3;        // swizzled k-offset
            const u16* src = Ut + (size_t)(bcol + n) * ENC_ + k0 + kc;
            u16* dst = &Blds[(size_t)(it * 512 + wid * 64) * 8];
            __builtin_amdgcn_global_load_lds(
                (const __attribute__((address_space(1))) void*)src,
                (__attribute__((address_space(3))) void*)dst, 16, 0, 0);
        }

        // ---- stage A: fp32 -> bf16 via regs, swizzled ds_write (2x 8 floats)
#pragma unroll
        for (int it = 0; it < 2; ++it) {
            int flat = (it * 512 + tid) * 8;          // logical u16 index
            int r = flat >> 6, c = flat & 63;
            const float* srcA = h + (size_t)(brow + r) * ENC_ + k0 + c;
            f32x4 v0 = *(const f32x4*)srcA;
            f32x4 v1 = *(const f32x4*)(srcA + 4);
            u16x8 w;
#pragma unroll
            for (int j = 0; j < 4; ++j) {
                __bf16 lo = (__bf16)v0[j], hi = (__bf16)v1[j];
                w[j]     = *(u16*)&lo;
                w[j + 4] = *(u16*)&hi;
            }
            *(u16x8*)&Alds[flat ^ ((r & 7) << 3)] = w;
        }
        __syncthreads();

#pragma unroll
        for (int kk = 0; kk < 2; ++kk) {
            bf16x8 af[4], bfr[4];
#pragma unroll
            for (int mf = 0; mf < 4; ++mf)
                af[mf] = *(const bf16x8*)&Alds[
                    (((wr * 64 + mf * 16 + lr) * 64) + kk * 32 + g * 8) ^ sw];
#pragma unroll
            for (int nf = 0; nf < 4; ++nf)
                bfr[nf] = *(const bf16x8*)&Blds[
                    (((wc * 64 + nf * 16 + lr) * 64) + kk * 32 + g * 8) ^ sw];
#pragma unroll
            for (int mf = 0; mf < 4; ++mf)
#pragma unroll
                for (int nf = 0; nf < 4; ++nf)
                    acc[mf][nf] = __builtin_amdgcn_mfma_f32_16x16x32_bf16(
                        af[mf], bfr[nf], acc[mf][nf], 0, 0, 0);
        }
        __syncthreads();
    }

    // ---- epilogue: e_partial[m] = sum_n tanh(acc + f2) * V ----
    float vv[4], ff[4];
#pragma unroll
    for (int nf = 0; nf < 4; ++nf) {
        int n = bcol + wc * 64 + nf * 16 + lr;
        vv[nf] = V[n];
        ff[nf] = f2[(size_t)b * A_ + n];
    }
    const int p = m * 4 + wc;                     // 8 partial slices
    float* ep = e_part + (size_t)p * M_ + brow + wr * 64;
#pragma unroll
    for (int mf = 0; mf < 4; ++mf) {
        float sums[4];
#pragma unroll
        for (int i = 0; i < 4; ++i) {
            float sv = 0.f;
#pragma unroll
            for (int nf = 0; nf < 4; ++nf) {
                float x = acc[mf][nf][i] + ff[nf];
                sv = fmaf(fast_tanh(x), vv[nf], sv);
            }
#pragma unroll
            for (int mm = 1; mm < 16; mm <<= 1)
                sv += __shfl_xor(sv, mm, 64);     // reduce 16 cols
            sums[i] = sv;
        }
        if (lr == 0) {
#pragma unroll
            for (int i = 0; i < 4; ++i)
                ep[mf * 16 + g * 4 + i] = sums[i];
        }
    }
}

// ---------------- softmax over T per batch --------------------------------
__global__ __launch_bounds__(256) void k_softmax(
        const float* __restrict__ e_part, float* __restrict__ a_out) {
    const int b = blockIdx.x, tid = threadIdx.x;
    const int lane = tid & 63, w = tid >> 6;
    __shared__ float red[4], red2[4];

    float ls[8];
    float lmax = -1e30f;
#pragma unroll
    for (int i = 0; i < 8; ++i) {
        size_t mm = (size_t)b * T_ + i * 256 + tid;
        float sv = 0.f;
#pragma unroll
        for (int p = 0; p < 8; ++p) sv += e_part[(size_t)p * M_ + mm];
        ls[i] = sv;
        lmax = fmaxf(lmax, sv);
    }
#pragma unroll
    for (int mm = 1; mm < 64; mm <<= 1) lmax = fmaxf(lmax, __shfl_xor(lmax, mm, 64));
    if (lane == 0) red[w] = lmax;
    __syncthreads();
    float bmax = fmaxf(fmaxf(red[0], red[1]), fmaxf(red[2], red[3]));

    float lsum = 0.f;
#pragma unroll
    for (int i = 0; i < 8; ++i) { ls[i] = __expf(ls[i] - bmax); lsum += ls[i]; }
#pragma unroll
    for (int mm = 1; mm < 64; mm <<= 1) lsum += __shfl_xor(lsum, mm, 64);
    if (lane == 0) red2[w] = lsum;
    __syncthreads();
    float inv = 1.0f / (red2[0] + red2[1] + red2[2] + red2[3]);

#pragma unroll
    for (int i = 0; i < 8; ++i)
        a_out[(size_t)b * T_ + i * 256 + tid] = ls[i] * inv;
}

// ---------------- context partials: c_part[tc][b][e], tc-chunk = 128 ------
__global__ __launch_bounds__(256) void k_ctx_part(
        const float* __restrict__ h, const float* __restrict__ a,
        float* __restrict__ c_part) {
    const int b = blockIdx.x, tc = blockIdx.y, tid = threadIdx.x;
    __shared__ float alds[128];
    if (tid < 128)
        alds[tid] = a[(size_t)b * T_ + tc * 128 + tid];
    __syncthreads();

    float4 acc = {0.f, 0.f, 0.f, 0.f};
    const float* hb = h + ((size_t)b * T_ + (size_t)tc * 128) * ENC_ + tid * 4;
    for (int t = 0; t < 128; ++t) {
        float av = alds[t];
        float4 hv = *(const float4*)(hb + (size_t)t * ENC_);
        acc.x = fmaf(av, hv.x, acc.x);
        acc.y = fmaf(av, hv.y, acc.y);
        acc.z = fmaf(av, hv.z, acc.z);
        acc.w = fmaf(av, hv.w, acc.w);
    }
    *(float4*)&c_part[((size_t)(tc * 64 + b)) * ENC_ + tid * 4] = acc;
}

// ---------------- final context reduce ------------------------------------
__global__ __launch_bounds__(256) void k_ctx_final(
        const float* __restrict__ c_part, float* __restrict__ c_out) {
    int idx = blockIdx.x * 256 + threadIdx.x;   // 16384 threads
    int off = idx * 4;
    float4 sv = {0.f, 0.f, 0.f, 0.f};
#pragma unroll
    for (int tc = 0; tc < 16; ++tc) {
        float4 v = *(const float4*)&c_part[(size_t)tc * 64 * 1024 + off];
        sv.x += v.x; sv.y += v.y; sv.z += v.z; sv.w += v.w;
    }
    *(float4*)&c_out[off] = sv;
}

extern "C" void kernel_launch(void* const* d_in, const int* in_sizes, int n_in,
                              void* d_out, int out_size, void* d_ws, size_t ws_size,
                              hipStream_t stream) {
    const float* h = (const float*)d_in[0];
    const float* s = (const float*)d_in[1];
    const float* U = (const float*)d_in[2];
    const float* W = (const float*)d_in[3];
    const float* V = (const float*)d_in[4];

    float* out   = (float*)d_out;
    float* c_out = out;                         // [64][1][1024] -> 65536 floats
    float* a_out = out + 64 * 1024;             // [64][2048][1] -> 131072 floats

    char* ws = (char*)d_ws;
    u16*   Ut     = (u16*)ws;                                       // 1 MB
    float* f2     = (float*)(ws + (1 << 20));                       // 128 KB
    float* e_part = (float*)(ws + (1 << 20) + (128 << 10));         // 4 MB
    float* c_part = e_part;   // overlay: e_part dead after k_softmax

    k_transpose_U<<<2048, 256, 0, stream>>>(U, Ut);
    k_f2<<<64, 256, 0, stream>>>(s, W, f2);

    k_gemm_e<<<2048, 512, 0, stream>>>(h, Ut, f2, V, e_part);

    k_softmax<<<64, 256, 0, stream>>>(e_part, a_out);

    dim3 gc(64, 16);
    k_ctx_part<<<gc, 256, 0, stream>>>(h, a_out, c_part);
    k_ctx_final<<<64, 256, 0, stream>>>(c_part, c_out);
}